// Round 1
// baseline (7075.534 us; speedup 1.0000x reference)
//
#include <hip/hip_runtime.h>

// Dilated 3-layer LSTM, T=512, B=128, D=H=256, rates {1,2,4}.
// Strategy: hidden-split (16 blocks) x batch-split (32 rows/block) persistent
// recurrence. Weights live in VGPRs as MFMA B-fragments (loaded once).
// Per-step h exchange via global fp16 ring + agent-scope release/acquire counter.
// Input projection fused into the MFMA (A = [x_t | h_{t-1}], K=512), x prefetched.

typedef _Float16 half8   __attribute__((ext_vector_type(8)));
typedef _Float16 half4_t __attribute__((ext_vector_type(4)));
typedef float    floatx4 __attribute__((ext_vector_type(4)));

#define GH 16                      // hidden-split blocks per batch group
#define NB 32                      // batch rows per block
#define RING_SLOTS 4
#define RING_STRIDE (512 * 256)    // fp16 elements per ring slot (max N = 512)
#define RING_BYTES  (RING_SLOTS * RING_STRIDE * 2)
#define CNT_INTS    6144           // 3 layers x 2048 counters

__device__ __forceinline__ float sigmf(float x) {
    return 1.0f / (1.0f + __expf(-x));
}
__device__ __forceinline__ float tanhfast(float x) {
    float e = __expf(-2.0f * fabsf(x));
    float r = (1.0f - e) / (1.0f + e);
    return copysignf(r, x);
}

__global__ __launch_bounds__(256) void lstm_layer_kernel(
    const float* __restrict__ in,    // (T_in=512, 128, 256) fp32 activations
    const float* __restrict__ Wih,   // [1024][256]
    const float* __restrict__ Whh,   // [1024][256]
    const float* __restrict__ bih,   // [1024]
    const float* __restrict__ bhh,   // [1024]
    float* __restrict__ out,         // (512, 128, 256) fp32
    _Float16* __restrict__ ring,     // [RING_SLOTS][512][256] fp16
    int* __restrict__ cnt,           // [G_b * td]
    int rate, int td, int G_b)
{
    // LDS: A tile [32 rows][520] fp16 (cols 0..255 = x_t, 256..511 = h_{t-1}, +8 pad)
    __shared__ _Float16 Abuf[NB][520];
    __shared__ float scr[NB][68];    // gates scratch [row][4*16 cols + pad]

    const int tid  = threadIdx.x;
    const int lane = tid & 63;
    const int wv   = tid >> 6;                 // wave 0..3 = gate chunk i,f,g,o
    const int g_b  = blockIdx.x % G_b;         // batch group (stride-G_b layout -> XCD locality)
    const int g_h  = blockIdx.x / G_b;         // hidden slice 0..15
    const int hid0 = g_h * 16;
    const int n0   = g_b * NB;

    // ---- Load B fragments (weights) into registers, once ----
    // wave wv owns gate rows [wv*256 + hid0, +16).
    // b-frag for K-step ks: lane holds B[k = ks*32 + (lane>>4)*8 + j][col = lane&15],
    // B[k][col] = Wcat[gate_row(col)][k], Wcat = [Wih | Whh] (K = 512).
    half8 bfrag[16];
    {
        const int col  = lane & 15;
        const int q    = lane >> 4;
        const int grow = wv * 256 + hid0 + col;
        const float* wih_row = Wih + (size_t)grow * 256;
        const float* whh_row = Whh + (size_t)grow * 256;
#pragma unroll
        for (int ks = 0; ks < 16; ++ks) {
            const int k0 = ks * 32 + q * 8;
            const float* src = (k0 < 256) ? (wih_row + k0) : (whh_row + (k0 - 256));
            floatx4 w0 = *(const floatx4*)(src);
            floatx4 w1 = *(const floatx4*)(src + 4);
            half8 hb;
            hb[0] = (_Float16)w0[0]; hb[1] = (_Float16)w0[1];
            hb[2] = (_Float16)w0[2]; hb[3] = (_Float16)w0[3];
            hb[4] = (_Float16)w1[0]; hb[5] = (_Float16)w1[1];
            hb[6] = (_Float16)w1[2]; hb[7] = (_Float16)w1[3];
            bfrag[ks] = hb;
        }
    }

    // ---- Elementwise lane mapping: (erow, ehid) and (erow+16, ehid) ----
    const int erow = tid >> 4;   // 0..15
    const int ehid = tid & 15;   // 0..15
    const float bi = bih[0 * 256 + hid0 + ehid] + bhh[0 * 256 + hid0 + ehid];
    const float bf = bih[1 * 256 + hid0 + ehid] + bhh[1 * 256 + hid0 + ehid];
    const float bg = bih[2 * 256 + hid0 + ehid] + bhh[2 * 256 + hid0 + ehid];
    const float bo = bih[3 * 256 + hid0 + ehid] + bhh[3 * 256 + hid0 + ehid];
    float c0 = 0.0f, c1 = 0.0f;  // cell state, register-resident

    // ---- Prefetch x(t=0): coalesced float4, thread -> (row = id>>6, col4 = id&63) ----
    floatx4 xp[8];
#pragma unroll
    for (int i = 0; i < 8; ++i) {
        int id  = tid + 256 * i;
        int row = id >> 6;
        int m   = n0 + row;
        const float* p = in + ((size_t)(0 * rate + (m >> 7)) * 128 + (m & 127)) * 256
                         + (size_t)(id & 63) * 4;
        xp[i] = *(const floatx4*)p;
    }

    for (int t = 0; t < td; ++t) {
        // 1. deposit x(t) -> Abuf cols [0,256) as fp16
#pragma unroll
        for (int i = 0; i < 8; ++i) {
            int id  = tid + 256 * i;
            int row = id >> 6;
            int c4  = (id & 63) * 4;
            half4_t hx;
            hx[0] = (_Float16)xp[i][0]; hx[1] = (_Float16)xp[i][1];
            hx[2] = (_Float16)xp[i][2]; hx[3] = (_Float16)xp[i][3];
            *(half4_t*)&Abuf[row][c4] = hx;
        }
        // 2. prefetch x(t+1) (dependency-free; lands during this step)
        if (t + 1 < td) {
#pragma unroll
            for (int i = 0; i < 8; ++i) {
                int id  = tid + 256 * i;
                int row = id >> 6;
                int m   = n0 + row;
                const float* p = in + ((size_t)((t + 1) * rate + (m >> 7)) * 128 + (m & 127)) * 256
                                 + (size_t)(id & 63) * 4;
                xp[i] = *(const floatx4*)p;
            }
        }
        // 3-4. wait for h(t-1) from the 16 sibling blocks, stage into Abuf cols [256,512)
        if (t > 0) {
            const int ci = g_b * td + (t - 1);
            if (tid == 0) {
                while (__hip_atomic_load(&cnt[ci], __ATOMIC_RELAXED,
                                         __HIP_MEMORY_SCOPE_AGENT) < GH) {
                    __builtin_amdgcn_s_sleep(1);
                }
            }
            __syncthreads();
            // per-thread acquire so every thread's subsequent ring reads are ordered
            (void)__hip_atomic_load(&cnt[ci], __ATOMIC_ACQUIRE, __HIP_MEMORY_SCOPE_AGENT);
            const _Float16* rs = ring + (size_t)((t - 1) & 3) * RING_STRIDE;
#pragma unroll
            for (int i = 0; i < 4; ++i) {
                int id  = tid + 256 * i;
                int row = id >> 5;
                int kc  = id & 31;
                int m   = n0 + row;
                uint4 v = *(const uint4*)(rs + (size_t)m * 256 + kc * 8);
                *(uint4*)&Abuf[row][256 + kc * 8] = v;
            }
        } else {
#pragma unroll
            for (int i = 0; i < 4; ++i) {
                int id  = tid + 256 * i;
                int row = id >> 5;
                int kc  = id & 31;
                uint4 z = {0u, 0u, 0u, 0u};
                *(uint4*)&Abuf[row][256 + kc * 8] = z;   // h0 = 0
            }
        }
        __syncthreads();

        // 6. MFMA: wave wv computes its 16-gate chunk for rows 0..15 and 16..31, K=512
        floatx4 acc0 = {0.f, 0.f, 0.f, 0.f};
        floatx4 acc1 = {0.f, 0.f, 0.f, 0.f};
        {
            const int r = lane & 15;
            const int q = lane >> 4;
#pragma unroll
            for (int ks = 0; ks < 16; ++ks) {
                half8 a0 = *(const half8*)&Abuf[r][ks * 32 + q * 8];
                half8 a1 = *(const half8*)&Abuf[16 + r][ks * 32 + q * 8];
                acc0 = __builtin_amdgcn_mfma_f32_16x16x32_f16(a0, bfrag[ks], acc0, 0, 0, 0);
                acc1 = __builtin_amdgcn_mfma_f32_16x16x32_f16(a1, bfrag[ks], acc1, 0, 0, 0);
            }
        }
        // 7. C-frag (col=lane&15, row=(lane>>4)*4+reg) -> gates scratch
        {
            const int r = lane & 15;
            const int q = lane >> 4;
#pragma unroll
            for (int reg = 0; reg < 4; ++reg) {
                scr[q * 4 + reg][wv * 16 + r]      = acc0[reg];
                scr[16 + q * 4 + reg][wv * 16 + r] = acc1[reg];
            }
        }
        __syncthreads();

        // 8-9. elementwise LSTM cell + stores (out fp32, ring fp16)
        {
            float gi0 = scr[erow][ehid]           + bi;
            float gf0 = scr[erow][16 + ehid]      + bf;
            float gg0 = scr[erow][32 + ehid]      + bg;
            float go0 = scr[erow][48 + ehid]      + bo;
            float gi1 = scr[16 + erow][ehid]      + bi;
            float gf1 = scr[16 + erow][16 + ehid] + bf;
            float gg1 = scr[16 + erow][32 + ehid] + bg;
            float go1 = scr[16 + erow][48 + ehid] + bo;

            c0 = sigmf(gf0) * c0 + sigmf(gi0) * tanhfast(gg0);
            c1 = sigmf(gf1) * c1 + sigmf(gi1) * tanhfast(gg1);
            float h0v = sigmf(go0) * tanhfast(c0);
            float h1v = sigmf(go1) * tanhfast(c1);

            int m0 = n0 + erow, m1 = m0 + 16;
            int tau0 = t * rate + (m0 >> 7);
            int tau1 = t * rate + (m1 >> 7);
            out[((size_t)tau0 * 128 + (m0 & 127)) * 256 + hid0 + ehid] = h0v;
            out[((size_t)tau1 * 128 + (m1 & 127)) * 256 + hid0 + ehid] = h1v;

            _Float16* rw = ring + (size_t)(t & 3) * RING_STRIDE;
            rw[(size_t)m0 * 256 + hid0 + ehid] = (_Float16)h0v;
            rw[(size_t)m1 * 256 + hid0 + ehid] = (_Float16)h1v;
        }

        // 10. release: all stores drained (barrier), then device-scope counter bump
        __syncthreads();
        if (tid == 0) {
            __hip_atomic_fetch_add(&cnt[g_b * td + t], 1, __ATOMIC_RELEASE,
                                   __HIP_MEMORY_SCOPE_AGENT);
        }
    }
}

extern "C" void kernel_launch(void* const* d_in, const int* in_sizes, int n_in,
                              void* d_out, int out_size, void* d_ws, size_t ws_size,
                              hipStream_t stream) {
    const float* x   = (const float*)d_in[0];
    const float* Wih = (const float*)d_in[1];   // (3, 1024, 256)
    const float* Whh = (const float*)d_in[2];   // (3, 1024, 256)
    const float* bih = (const float*)d_in[3];   // (3, 1024)
    const float* bhh = (const float*)d_in[4];   // (3, 1024)
    float* out = (float*)d_out;                 // (3, 512, 128, 256)

    _Float16* ring = (_Float16*)d_ws;
    int* cnt = (int*)((char*)d_ws + RING_BYTES);
    hipMemsetAsync(cnt, 0, CNT_INTS * sizeof(int), stream);

    const int rates[3]  = {1, 2, 4};
    const int cntOff[3] = {0, 2048, 4096};
    const float* in_ptr = x;
    for (int l = 0; l < 3; ++l) {
        const int rate = rates[l];
        const int td   = 512 / rate;
        const int N    = rate * 128;
        const int G_b  = N / NB;
        lstm_layer_kernel<<<dim3(G_b * GH), dim3(256), 0, stream>>>(
            in_ptr,
            Wih + (size_t)l * 1024 * 256,
            Whh + (size_t)l * 1024 * 256,
            bih + (size_t)l * 1024,
            bhh + (size_t)l * 1024,
            out + (size_t)l * 512 * 128 * 256,
            ring, cnt + cntOff[l],
            rate, td, G_b);
        in_ptr = out + (size_t)l * 512 * 128 * 256;
    }
}